// Round 9
// baseline (1092.521 us; speedup 1.0000x reference)
//
#include <hip/hip_runtime.h>

#define D 300
#define KP 320
#define NPAD 50048
#define NT128 391       // row-tiles of 128 (tiles 0..390)
#define PSL 392         // psum slots per column (padded)
#define PSLIVE 391
#define NGR 256
#define NL 5
#define NC 128
#define BN_EPS 1e-5f

typedef __attribute__((ext_vector_type(8))) short bf16x8;
typedef __attribute__((ext_vector_type(4))) float f32x4;
typedef unsigned short u16;

__device__ __forceinline__ void atomAdd(float* p, float v) { unsafeAtomicAdd(p, v); }

__device__ __forceinline__ short f2bf(float f) {
    union { float f; unsigned u; } v; v.f = f;
    unsigned r = v.u + 0x7fffu + ((v.u >> 16) & 1u);   // RNE
    return (short)(r >> 16);
}
__device__ __forceinline__ float bf2f(short s) {
    union { unsigned u; float f; } v;
    v.u = ((unsigned)(u16)s) << 16;
    return v.f;
}
// HW packed f32->bf16 (RNE), 1 instr per 2 values
__device__ __forceinline__ unsigned cvtpk(float lo, float hi) {
    unsigned r;
    asm("v_cvt_pk_bf16_f32 %0, %1, %2" : "=v"(r) : "v"(lo), "v"(hi));
    return r;
}
// DPP row_shr reduce over a 16-lane row: lane with (lane&15)==15 holds the sum.
template<int C>
__device__ __forceinline__ float rs_add(float v) {
    int x = __builtin_amdgcn_update_dpp(0, __float_as_int(v), C, 0xF, 0xF, true);
    return v + __int_as_float(x);
}
__device__ __forceinline__ float red16(float v) {
    v = rs_add<0x111>(v);   // row_shr:1
    v = rs_add<0x112>(v);   // row_shr:2
    v = rs_add<0x114>(v);   // row_shr:4
    v = rs_add<0x118>(v);   // row_shr:8
    return v;
}
// async global->LDS, 16B per lane; LDS dest lane-linear (base + lane*16)
__device__ __forceinline__ void gload_lds16(const u16* g, u16* l) {
    __builtin_amdgcn_global_load_lds((const __attribute__((address_space(1))) void*)g,
                                     (__attribute__((address_space(3))) void*)l, 16, 0, 0);
}

// ---------------------------------------------------------------------------
// offsets: off[g] = lower_bound(batch, g)
// ---------------------------------------------------------------------------
__global__ void offsets_kernel(const int* __restrict__ batch, int* __restrict__ off, int N) {
    int g = threadIdx.x;
    if (g > NGR) return;
    int lo = 0, hi = N;
    while (lo < hi) {
        int mid = (lo + hi) >> 1;
        if (batch[mid] < g) lo = mid + 1; else hi = mid;
    }
    off[g] = lo;
}

// ---------------------------------------------------------------------------
// CSR build: deg histogram -> hierarchical scan -> slot fill
// ---------------------------------------------------------------------------
__global__ __launch_bounds__(256)
void deg_kernel(const int* __restrict__ ei, int* __restrict__ deg, int E) {
    int e = blockIdx.x * 256 + threadIdx.x;
    if (e < E) atomicAdd(&deg[ei[E + e]], 1);
}

__global__ __launch_bounds__(256)
void degpart_kernel(const int* __restrict__ deg, int* __restrict__ part, int N) {
    int i = blockIdx.x * 256 + threadIdx.x;
    int v = (i < N) ? deg[i] : 0;
    #pragma unroll
    for (int o = 1; o < 64; o <<= 1) v += __shfl_xor(v, o);
    __shared__ int ws[4];
    if ((threadIdx.x & 63) == 0) ws[threadIdx.x >> 6] = v;
    __syncthreads();
    if (threadIdx.x == 0) part[blockIdx.x] = ws[0] + ws[1] + ws[2] + ws[3];
}

__global__ __launch_bounds__(256)
void partscan_kernel(int* __restrict__ part, int nb) {   // 1 block; nb <= 256
    __shared__ int buf[256];
    int t = threadIdx.x;
    int v = (t < nb) ? part[t] : 0;
    buf[t] = v;
    __syncthreads();
    for (int o = 1; o < 256; o <<= 1) {
        int u = (t >= o) ? buf[t - o] : 0;
        __syncthreads();
        buf[t] += u;
        __syncthreads();
    }
    if (t < nb) part[t] = (t == 0) ? 0 : buf[t - 1];   // exclusive
}

__global__ __launch_bounds__(256)
void rowptr_kernel(const int* __restrict__ deg, const int* __restrict__ part,
                   int* __restrict__ rowptr, int N, int E) {
    __shared__ int buf[256];
    int b = blockIdx.x, t = threadIdx.x;
    int i = b * 256 + t;
    int v = (i < N) ? deg[i] : 0;
    buf[t] = v;
    __syncthreads();
    for (int o = 1; o < 256; o <<= 1) {
        int u = (t >= o) ? buf[t - o] : 0;
        __syncthreads();
        buf[t] += u;
        __syncthreads();
    }
    if (i < N) rowptr[i] = part[b] + buf[t] - v;
    if (b == 0 && t == 0) rowptr[N] = E;
}

__global__ __launch_bounds__(256)
void fill_kernel(const int* __restrict__ ei, const int* __restrict__ rowptr,
                 int* __restrict__ cursor, int* __restrict__ col, int E) {
    int e = blockIdx.x * 256 + threadIdx.x;
    if (e >= E) return;
    int src = ei[e];
    int dst = ei[E + e];
    int pos = atomicAdd(&cursor[dst], 1);
    col[rowptr[dst] + pos] = src;
}

// ---------------------------------------------------------------------------
// weight convert: Wt[mat][n (320)][k (320)] = bf16(W[k][n]); pads zero
// ---------------------------------------------------------------------------
__global__ __launch_bounds__(256)
void wcvt_kernel(const float* __restrict__ W1, const float* __restrict__ W2,
                 u16* __restrict__ Wt) {
    int idx = blockIdx.x * 256 + threadIdx.x;
    if (idx >= 10 * KP * 80) return;
    int n4 = idx % 80;
    int k = (idx / 80) % KP;
    int mat = idx / (80 * KP);
    const float* Wsrc = (mat < NL) ? (W1 + (size_t)mat * D * D) : (W2 + (size_t)(mat - NL) * D * D);
    float4 w = make_float4(0.f, 0.f, 0.f, 0.f);
    if (k < D && n4 < 75) w = *(const float4*)(Wsrc + (size_t)k * D + n4 * 4);
    size_t base = ((size_t)mat * 320 + n4 * 4) * KP + k;
    Wt[base]          = (u16)f2bf(w.x);
    Wt[base + KP]     = (u16)f2bf(w.y);
    Wt[base + 2 * KP] = (u16)f2bf(w.z);
    Wt[base + 3 * KP] = (u16)f2bf(w.w);
}

// ---------------------------------------------------------------------------
// x convert: xbf[row][c] = bf16(x[row][c]), pads (c>=300, row>=N) zero
// ---------------------------------------------------------------------------
__global__ __launch_bounds__(256)
void xcvt_kernel(const float* __restrict__ x, u16* __restrict__ xbf, int N) {
    int idx = blockIdx.x * 256 + threadIdx.x;
    if (idx >= NPAD * 40) return;
    int row = idx / 40;
    int c8 = (idx - row * 40) * 8;
    short o[8];
    #pragma unroll
    for (int i = 0; i < 8; ++i) {
        int c = c8 + i;
        float f = (row < N && c < D) ? x[(size_t)row * D + c] : 0.f;
        o[i] = f2bf(f);
    }
    *(bf16x8*)(xbf + (size_t)row * KP + c8) = *(bf16x8*)o;
}

// ---------------------------------------------------------------------------
// gather with fused BN2+ReLU on source rows; edge loop unrolled x4.
// ---------------------------------------------------------------------------
template<bool APPLY>
__global__ __launch_bounds__(256)
void gather_kernel(const u16* __restrict__ H, u16* __restrict__ Z,
                   const int* __restrict__ rowptr, const int* __restrict__ col,
                   const float* __restrict__ scsh, int N) {
    int idx = blockIdx.x * 256 + threadIdx.x;
    if (idx >= N * 40) return;
    int node = idx / 40;
    int c8 = (idx - node * 40) * 8;
    float sc[8], sh[8];
    if (APPLY) {
        #pragma unroll
        for (int i = 0; i < 8; ++i) { sc[i] = scsh[c8 + i]; sh[i] = scsh[KP + c8 + i]; }
    }
    int s = rowptr[node], e = rowptr[node + 1];
    bf16x8 v = *(const bf16x8*)(H + (size_t)node * KP + c8);
    float acc[8];
    #pragma unroll
    for (int i = 0; i < 8; ++i) {
        float f = bf2f(v[i]);
        acc[i] = APPLY ? fmaxf(fmaf(f, sc[i], sh[i]), 0.f) : f;
    }
    int j = s;
    for (; j + 4 <= e; j += 4) {           // 4 row-loads in flight
        int s0 = col[j], s1 = col[j + 1], s2 = col[j + 2], s3 = col[j + 3];
        bf16x8 w0 = *(const bf16x8*)(H + (size_t)s0 * KP + c8);
        bf16x8 w1 = *(const bf16x8*)(H + (size_t)s1 * KP + c8);
        bf16x8 w2 = *(const bf16x8*)(H + (size_t)s2 * KP + c8);
        bf16x8 w3 = *(const bf16x8*)(H + (size_t)s3 * KP + c8);
        #pragma unroll
        for (int i = 0; i < 8; ++i) {
            float f0 = bf2f(w0[i]);
            float f1 = bf2f(w1[i]);
            float f2 = bf2f(w2[i]);
            float f3 = bf2f(w3[i]);
            acc[i] += APPLY ? fmaxf(fmaf(f0, sc[i], sh[i]), 0.f) : f0;
            acc[i] += APPLY ? fmaxf(fmaf(f1, sc[i], sh[i]), 0.f) : f1;
            acc[i] += APPLY ? fmaxf(fmaf(f2, sc[i], sh[i]), 0.f) : f2;
            acc[i] += APPLY ? fmaxf(fmaf(f3, sc[i], sh[i]), 0.f) : f3;
        }
    }
    for (; j < e; ++j) {
        int s0 = col[j];
        bf16x8 w0 = *(const bf16x8*)(H + (size_t)s0 * KP + c8);
        #pragma unroll
        for (int i = 0; i < 8; ++i) {
            float f0 = bf2f(w0[i]);
            acc[i] += APPLY ? fmaxf(fmaf(f0, sc[i], sh[i]), 0.f) : f0;
        }
    }
    short o[8];
    #pragma unroll
    for (int i = 0; i < 8; ++i) o[i] = f2bf(acc[i]);
    *(bf16x8*)(Z + (size_t)node * KP + c8) = *(bf16x8*)o;
}

// ---------------------------------------------------------------------------
// pool with optional fused BN2+ReLU; one block per graph, coalesced rows.
// ---------------------------------------------------------------------------
template<bool APPLY>
__global__ __launch_bounds__(320)
void pool_kernel(const u16* __restrict__ H, const int* __restrict__ off,
                 const float* __restrict__ scsh, float* __restrict__ pooled_l) {
    __shared__ float red[8][KP];
    int t = threadIdx.x;
    int g = blockIdx.x;
    int rq = t / 40;
    int c8 = (t - rq * 40) * 8;
    float sc[8], sh[8];
    if (APPLY) {
        #pragma unroll
        for (int i = 0; i < 8; ++i) { sc[i] = scsh[c8 + i]; sh[i] = scsh[KP + c8 + i]; }
    }
    int r0 = off[g], r1 = off[g + 1];
    float a[8] = {};
    for (int r = r0 + rq; r < r1; r += 8) {
        bf16x8 v = *(const bf16x8*)(H + (size_t)r * KP + c8);
        #pragma unroll
        for (int i = 0; i < 8; ++i) {
            float f = bf2f(v[i]);
            a[i] += APPLY ? fmaxf(fmaf(f, sc[i], sh[i]), 0.f) : f;
        }
    }
    #pragma unroll
    for (int i = 0; i < 8; ++i) red[rq][c8 + i] = a[i];
    __syncthreads();
    int c = t;
    if (c < D) {
        float s = 0.f;
        #pragma unroll
        for (int j = 0; j < 8; ++j) s += red[j][c];
        pooled_l[g * D + c] = s;
    }
}

// ---------------------------------------------------------------------------
// MFMA GEMM v10: register-free A path.
//   R1-R8 lesson: VGPR_Count never exceeded 76 -> hipcc ALWAYS sinks a
//   register A-prefetch; each load is consumed serially at 200-900cy ->
//   blocks live ~30k cycles for ~3k cycles of work.
//   v10: A tile (128x320 = 80KB) staged to LDS via global_load_lds (no dest
//   reg -> un-sinkable; 16 chunks/thread issue back-to-back, ONE drain at
//   the barrier). W in registers: wave owns 16 cols, bw[10] = 40 VGPR (a
//   size the allocator demonstrably keeps). A staged in MFMA-FRAGMENT order
//   ([rg][kc][lane], 1KB regions): gload_lds writes AND ds_read_b128 reads
//   are lane-linear -> ~0 bank conflicts (v7's layout was ~8-way).
//   2 blocks/CU (2x80KB = 160KB LDS): cross-block overlap hides the stage
//   drain (R3 lesson: no intra-block pipeline to get wrong).
//   APPLY: in-LDS repack, lane-linear mapping (wave covers kc={2w,2w+1}).
//   Stats: non-atomic psum[c][tile] (one writer per col per tile), no
//   stats barrier, no atomics. XCD remap kept (R6: FETCH 64->17MB).
// ---------------------------------------------------------------------------
template<bool APPLY>
__global__ __launch_bounds__(320, 2)
void mfma_gemm_kernel(const u16* __restrict__ Abf, const u16* __restrict__ Wt,
                      const float* __restrict__ scsh,
                      u16* __restrict__ Cbf, float* __restrict__ psum, int Nreal) {
    __shared__ u16 Ab[40960];               // 80 KB, fragment order
    const int tid = threadIdx.x;
    const int bid = blockIdx.x;
    const int xcd = bid & 7;
    const int pos = bid >> 3;
    const int tile = xcd + ((pos >> 2) << 3);   // 0..391, uniform
    const int nBase = (pos & 3) * 80;
    if (tile >= NT128) return;              // 4 dead blocks
    const int wave = tid >> 6;              // = nt, 0..4
    const int lane = tid & 63;
    const int quad = lane >> 4, l16 = lane & 15;

    // ---- W fragments -> registers (issued first; drain under staging)
    bf16x8 bw[10];
    {
        const u16* wp = Wt + (size_t)(nBase + wave * 16 + l16) * KP + quad * 8;
        #pragma unroll
        for (int kc = 0; kc < 10; ++kc) bw[kc] = *(const bf16x8*)(wp + kc * 32);
    }

    // ---- stage A tile: 5120 chunks of 16B in fragment order.
    //      chunk c: l16=c&15, quad=(c>>4)&3, kc=(c>>6)%10, rg=(c>>6)/10;
    //      LDS byte = c*16 (lane-linear); global = (rg*16+l16)*KP+kc*32+quad*8
    {
        const u16* base = Abf + (size_t)tile * 128 * KP;
        #pragma unroll
        for (int i = 0; i < 16; ++i) {
            int c = i * 320 + tid;
            int t6 = c >> 6;                       // 0..79
            int rg = (t6 * 205) >> 11;             // t6/10 (exact for 0..79)
            int kc = t6 - rg * 10;
            int go = (rg * 16 + l16) * KP + kc * 32 + quad * 8;
            gload_lds16(base + go, &Ab[c * 8]);
        }
    }
    __syncthreads();                        // drains staging + W loads

    if (APPLY) {
        // in-LDS repack h = relu(z*sc+sh); wave covers kc in {2w, 2w+1},
        // all 8 rg; lanes sweep a 1KB region linearly (conflict-free).
        float sca[2][8], sha[2][8];
        #pragma unroll
        for (int h = 0; h < 2; ++h) {
            int k0 = (2 * wave + h) * 32 + quad * 8;
            float4 s0 = *(const float4*)(scsh + k0);
            float4 s1 = *(const float4*)(scsh + k0 + 4);
            float4 h0 = *(const float4*)(scsh + KP + k0);
            float4 h1 = *(const float4*)(scsh + KP + k0 + 4);
            sca[h][0]=s0.x; sca[h][1]=s0.y; sca[h][2]=s0.z; sca[h][3]=s0.w;
            sca[h][4]=s1.x; sca[h][5]=s1.y; sca[h][6]=s1.z; sca[h][7]=s1.w;
            sha[h][0]=h0.x; sha[h][1]=h0.y; sha[h][2]=h0.z; sha[h][3]=h0.w;
            sha[h][4]=h1.x; sha[h][5]=h1.y; sha[h][6]=h1.z; sha[h][7]=h1.w;
        }
        #pragma unroll
        for (int j = 0; j < 16; ++j) {
            const int h = j & 1, rg = j >> 1;
            u16* p = &Ab[((rg * 10 + 2 * wave + h) << 9) + lane * 8];
            bf16x8 v = *(const bf16x8*)p;
            float f[8];
            #pragma unroll
            for (int i = 0; i < 8; ++i)
                f[i] = fmaxf(fmaf(bf2f(v[i]), sca[h][i], sha[h][i]), 0.f);
            union { unsigned u[4]; bf16x8 v; } o;
            o.u[0] = cvtpk(f[0], f[1]);
            o.u[1] = cvtpk(f[2], f[3]);
            o.u[2] = cvtpk(f[4], f[5]);
            o.u[3] = cvtpk(f[6], f[7]);
            *(bf16x8*)p = o.v;
        }
        __syncthreads();
    }

    // ---- MFMA: 80 lane-linear ds_read_b128, each feeding 1 MFMA;
    //      consecutive MFMAs hit different acc (kc outer, rg inner).
    const int lbase = lane * 8;
    f32x4 acc[8] = {};
    __builtin_amdgcn_s_setprio(1);
    #pragma unroll
    for (int kc = 0; kc < 10; ++kc) {
        #pragma unroll
        for (int rg = 0; rg < 8; ++rg) {
            bf16x8 af = *(const bf16x8*)&Ab[(((rg * 10 + kc)) << 9) + lbase];
            // swapped: D[n][m] = sum_k W[n][k] * A[m][k]
            acc[rg] = __builtin_amdgcn_mfma_f32_16x16x32_bf16(bw[kc], af, acc[rg], 0, 0, 0);
        }
    }
    __builtin_amdgcn_s_setprio(0);

    // ---- epilogue: thread owns cols c0..c0+3, rows rg*16+l16
    const int c0 = nBase + wave * 16 + quad * 4;
    u16* crow = Cbf + (size_t)(tile * 128 + l16) * KP + c0;
    float s[4] = {0.f, 0.f, 0.f, 0.f}, q[4] = {0.f, 0.f, 0.f, 0.f};
    #pragma unroll
    for (int rg = 0; rg < 8; ++rg) {
        const int row = tile * 128 + rg * 16 + l16;
        const bool ok = row < Nreal;
        float v0 = acc[rg][0], v1 = acc[rg][1], v2 = acc[rg][2], v3 = acc[rg][3];
        uint2 w;
        w.x = cvtpk(v0, v1);
        w.y = cvtpk(v2, v3);
        *(uint2*)(crow + (size_t)(rg * 16) * KP) = w;
        float m0 = ok ? v0 : 0.f, m1 = ok ? v1 : 0.f;
        float m2 = ok ? v2 : 0.f, m3 = ok ? v3 : 0.f;
        s[0] += m0; s[1] += m1; s[2] += m2; s[3] += m3;
        q[0] = fmaf(m0, m0, q[0]); q[1] = fmaf(m1, m1, q[1]);
        q[2] = fmaf(m2, m2, q[2]); q[3] = fmaf(m3, m3, q[3]);
    }
    #pragma unroll
    for (int r = 0; r < 4; ++r) {
        float sv = red16(s[r]);
        float qv = red16(q[r]);
        if (l16 == 15) {
            psum[(size_t)(c0 + r) * PSL + tile] = sv;
            psum[(size_t)(320 + c0 + r) * PSL + tile] = qv;
        }
    }
}

// ---------------------------------------------------------------------------
// BN finalize: one block per column reduces tile-partials (coalesced).
// ---------------------------------------------------------------------------
__global__ __launch_bounds__(256)
void bnfin_kernel(const float* __restrict__ psum, const float* __restrict__ g,
                  const float* __restrict__ be, float* __restrict__ scsh, float invN) {
    int c = blockIdx.x;                    // 0..D-1
    const float* ps = psum + (size_t)c * PSL;
    const float* pq = psum + (size_t)(320 + c) * PSL;
    float s1 = 0.f, s2 = 0.f;
    for (int i = threadIdx.x; i < PSLIVE; i += 256) { s1 += ps[i]; s2 += pq[i]; }
    #pragma unroll
    for (int o = 1; o < 64; o <<= 1) { s1 += __shfl_xor(s1, o); s2 += __shfl_xor(s2, o); }
    __shared__ float w1[4], w2[4];
    int wv = threadIdx.x >> 6;
    if ((threadIdx.x & 63) == 0) { w1[wv] = s1; w2[wv] = s2; }
    __syncthreads();
    if (threadIdx.x == 0) {
        float t1 = w1[0] + w1[1] + w1[2] + w1[3];
        float t2 = w2[0] + w2[1] + w2[2] + w2[3];
        float mu = t1 * invN;
        float var = t2 * invN - mu * mu;
        float s = g[c] / sqrtf(var + BN_EPS);
        scsh[c] = s;
        scsh[KP + c] = fmaf(-mu, s, be[c]);
    }
}

// ---------------------------------------------------------------------------
// readout
// ---------------------------------------------------------------------------
__global__ __launch_bounds__(128)
void bias_init_kernel(const float* __restrict__ fcb, float* __restrict__ out) {
    int i = blockIdx.x * 128 + threadIdx.x;
    if (i >= NGR * NC) return;
    int c = i & (NC - 1);
    float s = 0.f;
    for (int l = 0; l <= NL; ++l) s += fcb[l * NC + c];
    out[i] = s;
}

__global__ __launch_bounds__(128)
void readout_kernel(const float* __restrict__ pooled, const int* __restrict__ off,
                    const float* __restrict__ fcW, float* __restrict__ out) {
    __shared__ float sp[4][D];
    int c = threadIdx.x;
    int l = blockIdx.y;
    int g0 = blockIdx.x * 4;
    for (int i = c; i < 4 * D; i += 128) {
        int gg = i / D, k = i - gg * D;
        sp[gg][k] = pooled[((size_t)l * NGR + g0 + gg) * D + k];
    }
    __syncthreads();
    float acc[4] = {0.f, 0.f, 0.f, 0.f};
    for (int k = 0; k < D; ++k) {
        float w = fcW[((size_t)l * D + k) * NC + c];
        #pragma unroll
        for (int gg = 0; gg < 4; ++gg) acc[gg] = fmaf(sp[gg][k], w, acc[gg]);
    }
    #pragma unroll
    for (int gg = 0; gg < 4; ++gg) {
        int g = g0 + gg;
        float inv = 1.0f / fmaxf((float)(off[g + 1] - off[g]), 1.0f);
        atomAdd(&out[g * NC + c], acc[gg] * inv);
    }
}

// ---------------------------------------------------------------------------
extern "C" void kernel_launch(void* const* d_in, const int* in_sizes, int n_in,
                              void* d_out, int out_size, void* d_ws, size_t ws_size,
                              hipStream_t stream) {
    const float* x       = (const float*)d_in[0];
    const int*   ei      = (const int*)d_in[1];
    const int*   batch   = (const int*)d_in[2];
    const float* W1  = (const float*)d_in[3];
    const float* g1  = (const float*)d_in[5];
    const float* be1 = (const float*)d_in[6];
    const float* W2  = (const float*)d_in[7];
    const float* bng = (const float*)d_in[9];
    const float* bnb = (const float*)d_in[10];
    const float* fcW = (const float*)d_in[11];
    const float* fcb = (const float*)d_in[12];
    float* out = (float*)d_out;

    const int N = in_sizes[0] / D;   // 50000
    const int E = in_sizes[1] / 2;   // 400000
    const int nb = (N + 255) / 256;  // scan blocks

    u16* xbf  = (u16*)d_ws;                      // NPAD*KP  (dead after layer-0 gather)
    float* psum = (float*)d_ws;                  // overlay: 2*320*PSL floats (~1MB << 32MB)
    u16* bufA = xbf + (size_t)NPAD * KP;         // NPAD*KP
    u16* bufB = bufA + (size_t)NPAD * KP;        // NPAD*KP
    u16* Wt   = bufB + (size_t)NPAD * KP;        // 10*320*KP
    float* pooled = (float*)(Wt + (size_t)10 * 320 * KP);    // 6*NGR*D
    float* sc1    = pooled + (size_t)(NL + 1) * NGR * D;     // 2*KP
    float* sc2    = sc1 + 2 * KP;                            // 2*KP
    int*   off    = (int*)(sc2 + 2 * KP);                    // NGR+1
    int*   rowptr = off + NGR + 1;                           // N+1
    int*   cursor = rowptr + N + 1;                          // N
    int*   col    = cursor + N;                              // E
    int*   part   = col + E;                                 // 256

    hipMemsetAsync(sc1, 0, 4 * KP * sizeof(float), stream);  // sc1 + sc2 (pads stay 0)
    offsets_kernel<<<1, 320, 0, stream>>>(batch, off, N);
    bias_init_kernel<<<(NGR * NC + 127) / 128, 128, 0, stream>>>(fcb, out);

    // ---- CSR build (once) ----
    hipMemsetAsync(cursor, 0, N * sizeof(int), stream);
    deg_kernel<<<(E + 255) / 256, 256, 0, stream>>>(ei, cursor, E);
    degpart_kernel<<<nb, 256, 0, stream>>>(cursor, part, N);
    partscan_kernel<<<1, 256, 0, stream>>>(part, nb);
    rowptr_kernel<<<nb, 256, 0, stream>>>(cursor, part, rowptr, N, E);
    hipMemsetAsync(cursor, 0, N * sizeof(int), stream);
    fill_kernel<<<(E + 255) / 256, 256, 0, stream>>>(ei, rowptr, cursor, col, E);

    // ---- precompute bf16 weights + input ----
    wcvt_kernel<<<(10 * KP * 80 + 255) / 256, 256, 0, stream>>>(W1, W2, Wt);
    xcvt_kernel<<<(NPAD * 40 + 255) / 256, 256, 0, stream>>>(x, xbf, N);

    // grid: 8 XCD lanes x 49 tile-slots x 4 quarters; 320 threads (5 waves)
    const int gemm_blocks = 8 * 49 * 4;   // 1568; 4 dead (tile 391)
    const int nd40 = N * 40;
    float invN = 1.0f / (float)N;
    const size_t WtM = (size_t)320 * KP;

    // pooled[0] = sum of raw x rows per graph
    pool_kernel<false><<<NGR, 320, 0, stream>>>(xbf, off, sc2, pooled);

    u16* g = bufA;
    u16* t = bufB;
    const u16* src = xbf;
    for (int l = 0; l < NL; ++l) {
        // gather (+BN2/ReLU of prev layer for l>0): src -> g
        if (l == 0)
            gather_kernel<false><<<(nd40 + 255) / 256, 256, 0, stream>>>(src, g, rowptr, col, sc2, N);
        else
            gather_kernel<true><<<(nd40 + 255) / 256, 256, 0, stream>>>(src, g, rowptr, col, sc2, N);
        // GEMM1 (+tile partials): g @ W1 -> t   (bias folded into BN)
        mfma_gemm_kernel<false><<<gemm_blocks, 320, 0, stream>>>(
            g, Wt + (size_t)l * WtM, sc1, t, psum, N);
        bnfin_kernel<<<D, 256, 0, stream>>>(psum, g1 + l * D, be1 + l * D, sc1, invN);
        // GEMM2 (BN1+ReLU via in-LDS repack, +tile partials): t @ W2 -> g
        mfma_gemm_kernel<true><<<gemm_blocks, 320, 0, stream>>>(
            t, Wt + (size_t)(NL + l) * WtM, sc1, g, psum, N);
        bnfin_kernel<<<D, 256, 0, stream>>>(psum, bng + l * D, bnb + l * D, sc2, invN);
        // pooled[l+1] = per-graph sum of relu(bn2(z_l)) via on-the-fly apply
        pool_kernel<true><<<NGR, 320, 0, stream>>>(g, off, sc2, pooled + (size_t)(l + 1) * NGR * D);
        src = g;
        u16* tmp = g; g = t; t = tmp;
    }
    readout_kernel<<<dim3(NGR / 4, NL + 1), 128, 0, stream>>>(pooled, off, fcW, out);
}

// Round 10
// 1008.547 us; speedup vs baseline: 1.0833x; 1.0833x over previous
//
#include <hip/hip_runtime.h>

#define D 300
#define KP 320
#define NPAD 50048
#define NT128 391       // row-tiles of 128 (tiles 0..390)
#define PSL 1568        // psum slots per column = 392 tiles * 4 waves
#define PSLIVE 1564     // live slots = 391 * 4
#define WSTRIDE 328     // LDS k-stride (u16)
#define NGR 256
#define NL 5
#define NC 128
#define BN_EPS 1e-5f

typedef __attribute__((ext_vector_type(8))) short bf16x8;
typedef __attribute__((ext_vector_type(4))) float f32x4;
typedef unsigned short u16;

__device__ __forceinline__ void atomAdd(float* p, float v) { unsafeAtomicAdd(p, v); }

__device__ __forceinline__ short f2bf(float f) {
    union { float f; unsigned u; } v; v.f = f;
    unsigned r = v.u + 0x7fffu + ((v.u >> 16) & 1u);   // RNE
    return (short)(r >> 16);
}
__device__ __forceinline__ float bf2f(short s) {
    union { unsigned u; float f; } v;
    v.u = ((unsigned)(u16)s) << 16;
    return v.f;
}
// HW packed f32->bf16 (RNE), 1 instr per 2 values
__device__ __forceinline__ unsigned cvtpk(float lo, float hi) {
    unsigned r;
    asm("v_cvt_pk_bf16_f32 %0, %1, %2" : "=v"(r) : "v"(lo), "v"(hi));
    return r;
}
// DPP row_shr reduce over a 16-lane row: lanes 15/31/47/63 hold their row's sum.
template<int C>
__device__ __forceinline__ float rs_add(float v) {
    int x = __builtin_amdgcn_update_dpp(0, __float_as_int(v), C, 0xF, 0xF, true);
    return v + __int_as_float(x);
}
__device__ __forceinline__ float red16(float v) {
    v = rs_add<0x111>(v);   // row_shr:1
    v = rs_add<0x112>(v);   // row_shr:2
    v = rs_add<0x114>(v);   // row_shr:4
    v = rs_add<0x118>(v);   // row_shr:8
    return v;
}

// ---------------------------------------------------------------------------
// offsets: off[g] = lower_bound(batch, g)
// ---------------------------------------------------------------------------
__global__ void offsets_kernel(const int* __restrict__ batch, int* __restrict__ off, int N) {
    int g = threadIdx.x;
    if (g > NGR) return;
    int lo = 0, hi = N;
    while (lo < hi) {
        int mid = (lo + hi) >> 1;
        if (batch[mid] < g) lo = mid + 1; else hi = mid;
    }
    off[g] = lo;
}

// ---------------------------------------------------------------------------
// CSR build: deg histogram -> hierarchical scan -> slot fill
// ---------------------------------------------------------------------------
__global__ __launch_bounds__(256)
void deg_kernel(const int* __restrict__ ei, int* __restrict__ deg, int E) {
    int e = blockIdx.x * 256 + threadIdx.x;
    if (e < E) atomicAdd(&deg[ei[E + e]], 1);
}

__global__ __launch_bounds__(256)
void degpart_kernel(const int* __restrict__ deg, int* __restrict__ part, int N) {
    int i = blockIdx.x * 256 + threadIdx.x;
    int v = (i < N) ? deg[i] : 0;
    #pragma unroll
    for (int o = 1; o < 64; o <<= 1) v += __shfl_xor(v, o);
    __shared__ int ws[4];
    if ((threadIdx.x & 63) == 0) ws[threadIdx.x >> 6] = v;
    __syncthreads();
    if (threadIdx.x == 0) part[blockIdx.x] = ws[0] + ws[1] + ws[2] + ws[3];
}

__global__ __launch_bounds__(256)
void partscan_kernel(int* __restrict__ part, int nb) {   // 1 block; nb <= 256
    __shared__ int buf[256];
    int t = threadIdx.x;
    int v = (t < nb) ? part[t] : 0;
    buf[t] = v;
    __syncthreads();
    for (int o = 1; o < 256; o <<= 1) {
        int u = (t >= o) ? buf[t - o] : 0;
        __syncthreads();
        buf[t] += u;
        __syncthreads();
    }
    if (t < nb) part[t] = (t == 0) ? 0 : buf[t - 1];   // exclusive
}

__global__ __launch_bounds__(256)
void rowptr_kernel(const int* __restrict__ deg, const int* __restrict__ part,
                   int* __restrict__ rowptr, int N, int E) {
    __shared__ int buf[256];
    int b = blockIdx.x, t = threadIdx.x;
    int i = b * 256 + t;
    int v = (i < N) ? deg[i] : 0;
    buf[t] = v;
    __syncthreads();
    for (int o = 1; o < 256; o <<= 1) {
        int u = (t >= o) ? buf[t - o] : 0;
        __syncthreads();
        buf[t] += u;
        __syncthreads();
    }
    if (i < N) rowptr[i] = part[b] + buf[t] - v;
    if (b == 0 && t == 0) rowptr[N] = E;
}

__global__ __launch_bounds__(256)
void fill_kernel(const int* __restrict__ ei, const int* __restrict__ rowptr,
                 int* __restrict__ cursor, int* __restrict__ col, int E) {
    int e = blockIdx.x * 256 + threadIdx.x;
    if (e >= E) return;
    int src = ei[e];
    int dst = ei[E + e];
    int pos = atomicAdd(&cursor[dst], 1);
    col[rowptr[dst] + pos] = src;
}

// ---------------------------------------------------------------------------
// weight convert: Wt[mat][n (320)][k (320)] = bf16(W[k][n]); pads zero
// ---------------------------------------------------------------------------
__global__ __launch_bounds__(256)
void wcvt_kernel(const float* __restrict__ W1, const float* __restrict__ W2,
                 u16* __restrict__ Wt) {
    int idx = blockIdx.x * 256 + threadIdx.x;
    if (idx >= 10 * KP * 80) return;
    int n4 = idx % 80;
    int k = (idx / 80) % KP;
    int mat = idx / (80 * KP);
    const float* Wsrc = (mat < NL) ? (W1 + (size_t)mat * D * D) : (W2 + (size_t)(mat - NL) * D * D);
    float4 w = make_float4(0.f, 0.f, 0.f, 0.f);
    if (k < D && n4 < 75) w = *(const float4*)(Wsrc + (size_t)k * D + n4 * 4);
    size_t base = ((size_t)mat * 320 + n4 * 4) * KP + k;
    Wt[base]          = (u16)f2bf(w.x);
    Wt[base + KP]     = (u16)f2bf(w.y);
    Wt[base + 2 * KP] = (u16)f2bf(w.z);
    Wt[base + 3 * KP] = (u16)f2bf(w.w);
}

// ---------------------------------------------------------------------------
// x convert: xbf[row][c] = bf16(x[row][c]), pads (c>=300, row>=N) zero
// ---------------------------------------------------------------------------
__global__ __launch_bounds__(256)
void xcvt_kernel(const float* __restrict__ x, u16* __restrict__ xbf, int N) {
    int idx = blockIdx.x * 256 + threadIdx.x;
    if (idx >= NPAD * 40) return;
    int row = idx / 40;
    int c8 = (idx - row * 40) * 8;
    short o[8];
    #pragma unroll
    for (int i = 0; i < 8; ++i) {
        int c = c8 + i;
        float f = (row < N && c < D) ? x[(size_t)row * D + c] : 0.f;
        o[i] = f2bf(f);
    }
    *(bf16x8*)(xbf + (size_t)row * KP + c8) = *(bf16x8*)o;
}

// ---------------------------------------------------------------------------
// gather with fused BN2+ReLU on source rows; edge loop 8/4/2/1-wide
// (avg degree 8: the 8-wide head covers ~55% of nodes in one round of
// in-flight loads instead of two serial 4-deep rounds).
// ---------------------------------------------------------------------------
template<bool APPLY>
__global__ __launch_bounds__(256)
void gather_kernel(const u16* __restrict__ H, u16* __restrict__ Z,
                   const int* __restrict__ rowptr, const int* __restrict__ col,
                   const float* __restrict__ scsh, int N) {
    int idx = blockIdx.x * 256 + threadIdx.x;
    if (idx >= N * 40) return;
    int node = idx / 40;
    int c8 = (idx - node * 40) * 8;
    float sc[8], sh[8];
    if (APPLY) {
        #pragma unroll
        for (int i = 0; i < 8; ++i) { sc[i] = scsh[c8 + i]; sh[i] = scsh[KP + c8 + i]; }
    }
    int s = rowptr[node], e = rowptr[node + 1];
    bf16x8 v = *(const bf16x8*)(H + (size_t)node * KP + c8);
    float acc[8];
    #pragma unroll
    for (int i = 0; i < 8; ++i) {
        float f = bf2f(v[i]);
        acc[i] = APPLY ? fmaxf(fmaf(f, sc[i], sh[i]), 0.f) : f;
    }
    int j = s;
    for (; j + 8 <= e; j += 8) {           // 8 row-loads in flight
        bf16x8 w[8];
        #pragma unroll
        for (int u = 0; u < 8; ++u)
            w[u] = *(const bf16x8*)(H + (size_t)col[j + u] * KP + c8);
        #pragma unroll
        for (int u = 0; u < 8; ++u) {
            #pragma unroll
            for (int i = 0; i < 8; ++i) {
                float f = bf2f(w[u][i]);
                acc[i] += APPLY ? fmaxf(fmaf(f, sc[i], sh[i]), 0.f) : f;
            }
        }
    }
    if (j + 4 <= e) {
        bf16x8 w[4];
        #pragma unroll
        for (int u = 0; u < 4; ++u)
            w[u] = *(const bf16x8*)(H + (size_t)col[j + u] * KP + c8);
        #pragma unroll
        for (int u = 0; u < 4; ++u) {
            #pragma unroll
            for (int i = 0; i < 8; ++i) {
                float f = bf2f(w[u][i]);
                acc[i] += APPLY ? fmaxf(fmaf(f, sc[i], sh[i]), 0.f) : f;
            }
        }
        j += 4;
    }
    if (j + 2 <= e) {
        bf16x8 w0 = *(const bf16x8*)(H + (size_t)col[j] * KP + c8);
        bf16x8 w1 = *(const bf16x8*)(H + (size_t)col[j + 1] * KP + c8);
        #pragma unroll
        for (int i = 0; i < 8; ++i) {
            float f0 = bf2f(w0[i]);
            float f1 = bf2f(w1[i]);
            acc[i] += APPLY ? fmaxf(fmaf(f0, sc[i], sh[i]), 0.f) : f0;
            acc[i] += APPLY ? fmaxf(fmaf(f1, sc[i], sh[i]), 0.f) : f1;
        }
        j += 2;
    }
    if (j < e) {
        bf16x8 w0 = *(const bf16x8*)(H + (size_t)col[j] * KP + c8);
        #pragma unroll
        for (int i = 0; i < 8; ++i) {
            float f0 = bf2f(w0[i]);
            acc[i] += APPLY ? fmaxf(fmaf(f0, sc[i], sh[i]), 0.f) : f0;
        }
    }
    short o[8];
    #pragma unroll
    for (int i = 0; i < 8; ++i) o[i] = f2bf(acc[i]);
    *(bf16x8*)(Z + (size_t)node * KP + c8) = *(bf16x8*)o;
}

// ---------------------------------------------------------------------------
// pool with optional fused BN2+ReLU; one block per graph, coalesced rows.
// ---------------------------------------------------------------------------
template<bool APPLY>
__global__ __launch_bounds__(320)
void pool_kernel(const u16* __restrict__ H, const int* __restrict__ off,
                 const float* __restrict__ scsh, float* __restrict__ pooled_l) {
    __shared__ float red[8][KP];
    int t = threadIdx.x;
    int g = blockIdx.x;
    int rq = t / 40;
    int c8 = (t - rq * 40) * 8;
    float sc[8], sh[8];
    if (APPLY) {
        #pragma unroll
        for (int i = 0; i < 8; ++i) { sc[i] = scsh[c8 + i]; sh[i] = scsh[KP + c8 + i]; }
    }
    int r0 = off[g], r1 = off[g + 1];
    float a[8] = {};
    for (int r = r0 + rq; r < r1; r += 8) {
        bf16x8 v = *(const bf16x8*)(H + (size_t)r * KP + c8);
        #pragma unroll
        for (int i = 0; i < 8; ++i) {
            float f = bf2f(v[i]);
            a[i] += APPLY ? fmaxf(fmaf(f, sc[i], sh[i]), 0.f) : f;
        }
    }
    #pragma unroll
    for (int i = 0; i < 8; ++i) red[rq][c8 + i] = a[i];
    __syncthreads();
    int c = t;
    if (c < D) {
        float s = 0.f;
        #pragma unroll
        for (int j = 0; j < 8; ++j) s += red[j][c];
        pooled_l[g * D + c] = s;
    }
}

// ---------------------------------------------------------------------------
// MFMA GEMM v11 = v7 (proven 45.7us) + de-atomized stats retirement:
//   - identical data path: 128x80 tile, A-loads at entry + pins, W quarter
//     in LDS (swizzled), XCD remap (FETCH 64->17MB), setprio MFMA loop.
//   - R9 lesson: v8/v9/v10 each traded away a v7 property (co-residency,
//     no-spill regs, coalesced loads) and lost. v11 changes ONLY the
//     retirement path: epilogue's red16 lanes (15/31/47/63 per wave) write
//     psum[c][tile*4+wave] NON-atomically; barrier-2, LDS lsum/lsq and all
//     global atomics deleted -> waves retire at their last C-store.
//     (psum scheme verified correct in R8/R9 runs.)
// ---------------------------------------------------------------------------
template<bool APPLY>
__global__ __launch_bounds__(256, 3)
void mfma_gemm_kernel(const u16* __restrict__ Abf, const u16* __restrict__ Wt,
                      const float* __restrict__ scsh,
                      u16* __restrict__ Cbf, float* __restrict__ psum, int Nreal) {
    __shared__ u16 Ws[80 * WSTRIDE];        // 52.5 KB
    const int tid = threadIdx.x;
    const int bid = blockIdx.x;
    const int xcd = bid & 7;
    const int pos = bid >> 3;
    const int tile = xcd + ((pos >> 2) << 3);   // 0..391, uniform
    const int nBase = (pos & 3) * 80;
    if (tile >= NT128) return;              // 4 dead blocks; psum slots unread
    const int wave = tid >> 6, lane = tid & 63;
    const int quad = lane >> 4, l16 = lane & 15;

    // ---- A-loads FIRST (oldest in VMEM queue): wave covers rows
    //      tile*128 + wave*16 + l16 (+64)
    const u16* pA = Abf + (size_t)(tile * 128 + wave * 16 + l16) * KP + quad * 8;
    bf16x8 a[2][10];
    #pragma unroll
    for (int kc = 0; kc < 10; ++kc) {
        a[0][kc] = *(const bf16x8*)(pA + kc * 32);
        a[1][kc] = *(const bf16x8*)(pA + (size_t)64 * KP + kc * 32);
    }

    // ---- stage W quarter: 80 n-rows x 320 k, quad-slot XOR swizzle
    {
        const u16* src = Wt + (size_t)nBase * KP;
        for (int unit = tid; unit < 80 * 40; unit += 256) {
            int n = unit / 40, kg = unit - n * 40;
            int kc = kg >> 2, q = kg & 3;
            *(bf16x8*)&Ws[n * WSTRIDE + kc * 32 + ((q ^ (n & 3)) << 3)] =
                *(const bf16x8*)(src + (size_t)n * KP + kg * 8);
        }
    }

    // ---- pin A fragments before the barrier (barrier drains vmcnt anyway)
    #pragma unroll
    for (int kc = 0; kc < 10; ++kc) {
        asm volatile("" : "+v"(a[0][kc]));
        asm volatile("" : "+v"(a[1][kc]));
    }
    __syncthreads();                        // the ONLY barrier

    if (APPLY) {
        #pragma unroll
        for (int kc = 0; kc < 10; ++kc) {
            const float* sp = scsh + kc * 32 + quad * 8;
            float4 s0 = *(const float4*)sp;
            float4 s1 = *(const float4*)(sp + 4);
            float4 h0 = *(const float4*)(sp + KP);
            float4 h1 = *(const float4*)(sp + KP + 4);
            float sc[8] = {s0.x, s0.y, s0.z, s0.w, s1.x, s1.y, s1.z, s1.w};
            float sh[8] = {h0.x, h0.y, h0.z, h0.w, h1.x, h1.y, h1.z, h1.w};
            #pragma unroll
            for (int g = 0; g < 2; ++g) {
                float f[8];
                #pragma unroll
                for (int i = 0; i < 8; ++i)
                    f[i] = fmaxf(fmaf(bf2f(a[g][kc][i]), sc[i], sh[i]), 0.f);
                union { unsigned u[4]; bf16x8 v; } o;
                o.u[0] = cvtpk(f[0], f[1]);
                o.u[1] = cvtpk(f[2], f[3]);
                o.u[2] = cvtpk(f[4], f[5]);
                o.u[3] = cvtpk(f[6], f[7]);
                a[g][kc] = o.v;
            }
        }
    }

    // per-wave LDS read bases for the 5 n-subtiles (swizzled quad slot baked in)
    int wb[5];
    #pragma unroll
    for (int nt = 0; nt < 5; ++nt)
        wb[nt] = (nt * 16 + l16) * WSTRIDE + ((quad ^ (l16 & 3)) << 3);

    f32x4 acc[2][5] = {};
    __builtin_amdgcn_s_setprio(1);
    #pragma unroll
    for (int kc = 0; kc < 10; ++kc) {
        #pragma unroll
        for (int nt = 0; nt < 5; ++nt) {
            bf16x8 b = *(const bf16x8*)&Ws[wb[nt] + kc * 32];
            // swapped: D[n][m] = sum_k W[n][k] * A[m][k]
            acc[0][nt] = __builtin_amdgcn_mfma_f32_16x16x32_bf16(b, a[0][kc], acc[0][nt], 0, 0, 0);
            acc[1][nt] = __builtin_amdgcn_mfma_f32_16x16x32_bf16(b, a[1][kc], acc[1][nt], 0, 0, 0);
        }
    }
    __builtin_amdgcn_s_setprio(0);

    // ---- epilogue: thread owns rows {r0g, r0g+64}, cols quad*4..+3 per nt;
    //      stats via red16 -> direct non-atomic psum (no barrier, no atomics)
    const int r0g = tile * 128 + wave * 16 + l16;
    const bool ok0 = r0g < Nreal, ok1 = (r0g + 64) < Nreal;
    u16* crow0 = Cbf + (size_t)r0g * KP + nBase + quad * 4;
    u16* crow1 = crow0 + (size_t)64 * KP;
    const int pslot = tile * 4 + wave;
    float* psq = psum + (size_t)320 * PSL;
    #pragma unroll
    for (int nt = 0; nt < 5; ++nt) {
        float v0[4], v1[4];
        #pragma unroll
        for (int r = 0; r < 4; ++r) { v0[r] = acc[0][nt][r]; v1[r] = acc[1][nt][r]; }
        uint2 w0, w1;
        w0.x = cvtpk(v0[0], v0[1]); w0.y = cvtpk(v0[2], v0[3]);
        w1.x = cvtpk(v1[0], v1[1]); w1.y = cvtpk(v1[2], v1[3]);
        *(uint2*)(crow0 + nt * 16) = w0;
        *(uint2*)(crow1 + nt * 16) = w1;
        #pragma unroll
        for (int r = 0; r < 4; ++r) {
            float s0 = ok0 ? v0[r] : 0.f;
            float s1 = ok1 ? v1[r] : 0.f;
            float sv = red16(s0 + s1);
            float qv = red16(fmaf(s0, s0, s1 * s1));
            if (l16 == 15) {                 // lanes 15/31/47/63: one per quad
                int c = nBase + nt * 16 + quad * 4 + r;
                psum[(size_t)c * PSL + pslot] = sv;
                psq [(size_t)c * PSL + pslot] = qv;
            }
        }
    }
}

// ---------------------------------------------------------------------------
// BN finalize: one block per column reduces live wave-partials (coalesced).
// ---------------------------------------------------------------------------
__global__ __launch_bounds__(256)
void bnfin_kernel(const float* __restrict__ psum, const float* __restrict__ g,
                  const float* __restrict__ be, float* __restrict__ scsh, float invN) {
    int c = blockIdx.x;                    // 0..D-1
    const float* ps = psum + (size_t)c * PSL;
    const float* pq = psum + (size_t)(320 + c) * PSL;
    float s1 = 0.f, s2 = 0.f;
    for (int i = threadIdx.x; i < PSLIVE; i += 256) { s1 += ps[i]; s2 += pq[i]; }
    #pragma unroll
    for (int o = 1; o < 64; o <<= 1) { s1 += __shfl_xor(s1, o); s2 += __shfl_xor(s2, o); }
    __shared__ float w1[4], w2[4];
    int wv = threadIdx.x >> 6;
    if ((threadIdx.x & 63) == 0) { w1[wv] = s1; w2[wv] = s2; }
    __syncthreads();
    if (threadIdx.x == 0) {
        float t1 = w1[0] + w1[1] + w1[2] + w1[3];
        float t2 = w2[0] + w2[1] + w2[2] + w2[3];
        float mu = t1 * invN;
        float var = t2 * invN - mu * mu;
        float s = g[c] / sqrtf(var + BN_EPS);
        scsh[c] = s;
        scsh[KP + c] = fmaf(-mu, s, be[c]);
    }
}

// ---------------------------------------------------------------------------
// readout
// ---------------------------------------------------------------------------
__global__ __launch_bounds__(128)
void bias_init_kernel(const float* __restrict__ fcb, float* __restrict__ out) {
    int i = blockIdx.x * 128 + threadIdx.x;
    if (i >= NGR * NC) return;
    int c = i & (NC - 1);
    float s = 0.f;
    for (int l = 0; l <= NL; ++l) s += fcb[l * NC + c];
    out[i] = s;
}

__global__ __launch_bounds__(128)
void readout_kernel(const float* __restrict__ pooled, const int* __restrict__ off,
                    const float* __restrict__ fcW, float* __restrict__ out) {
    __shared__ float sp[4][D];
    int c = threadIdx.x;
    int l = blockIdx.y;
    int g0 = blockIdx.x * 4;
    for (int i = c; i < 4 * D; i += 128) {
        int gg = i / D, k = i - gg * D;
        sp[gg][k] = pooled[((size_t)l * NGR + g0 + gg) * D + k];
    }
    __syncthreads();
    float acc[4] = {0.f, 0.f, 0.f, 0.f};
    for (int k = 0; k < D; ++k) {
        float w = fcW[((size_t)l * D + k) * NC + c];
        #pragma unroll
        for (int gg = 0; gg < 4; ++gg) acc[gg] = fmaf(sp[gg][k], w, acc[gg]);
    }
    #pragma unroll
    for (int gg = 0; gg < 4; ++gg) {
        int g = g0 + gg;
        float inv = 1.0f / fmaxf((float)(off[g + 1] - off[g]), 1.0f);
        atomAdd(&out[g * NC + c], acc[gg] * inv);
    }
}

// ---------------------------------------------------------------------------
extern "C" void kernel_launch(void* const* d_in, const int* in_sizes, int n_in,
                              void* d_out, int out_size, void* d_ws, size_t ws_size,
                              hipStream_t stream) {
    const float* x       = (const float*)d_in[0];
    const int*   ei      = (const int*)d_in[1];
    const int*   batch   = (const int*)d_in[2];
    const float* W1  = (const float*)d_in[3];
    const float* g1  = (const float*)d_in[5];
    const float* be1 = (const float*)d_in[6];
    const float* W2  = (const float*)d_in[7];
    const float* bng = (const float*)d_in[9];
    const float* bnb = (const float*)d_in[10];
    const float* fcW = (const float*)d_in[11];
    const float* fcb = (const float*)d_in[12];
    float* out = (float*)d_out;

    const int N = in_sizes[0] / D;   // 50000
    const int E = in_sizes[1] / 2;   // 400000
    const int nb = (N + 255) / 256;  // scan blocks

    u16* xbf  = (u16*)d_ws;                      // NPAD*KP  (dead after layer-0 gather)
    float* psum = (float*)d_ws;                  // overlay: 2*320*PSL floats (~4MB << 32MB)
    u16* bufA = xbf + (size_t)NPAD * KP;         // NPAD*KP
    u16* bufB = bufA + (size_t)NPAD * KP;        // NPAD*KP
    u16* Wt   = bufB + (size_t)NPAD * KP;        // 10*320*KP
    float* pooled = (float*)(Wt + (size_t)10 * 320 * KP);    // 6*NGR*D
    float* sc1    = pooled + (size_t)(NL + 1) * NGR * D;     // 2*KP
    float* sc2    = sc1 + 2 * KP;                            // 2*KP
    int*   off    = (int*)(sc2 + 2 * KP);                    // NGR+1
    int*   rowptr = off + NGR + 1;                           // N+1
    int*   cursor = rowptr + N + 1;                          // N
    int*   col    = cursor + N;                              // E
    int*   part   = col + E;                                 // 256

    hipMemsetAsync(sc1, 0, 4 * KP * sizeof(float), stream);  // sc1 + sc2 (pads stay 0)
    offsets_kernel<<<1, 320, 0, stream>>>(batch, off, N);
    bias_init_kernel<<<(NGR * NC + 127) / 128, 128, 0, stream>>>(fcb, out);

    // ---- CSR build (once) ----
    hipMemsetAsync(cursor, 0, N * sizeof(int), stream);
    deg_kernel<<<(E + 255) / 256, 256, 0, stream>>>(ei, cursor, E);
    degpart_kernel<<<nb, 256, 0, stream>>>(cursor, part, N);
    partscan_kernel<<<1, 256, 0, stream>>>(part, nb);
    rowptr_kernel<<<nb, 256, 0, stream>>>(cursor, part, rowptr, N, E);
    hipMemsetAsync(cursor, 0, N * sizeof(int), stream);
    fill_kernel<<<(E + 255) / 256, 256, 0, stream>>>(ei, rowptr, cursor, col, E);

    // ---- precompute bf16 weights + input ----
    wcvt_kernel<<<(10 * KP * 80 + 255) / 256, 256, 0, stream>>>(W1, W2, Wt);
    xcvt_kernel<<<(NPAD * 40 + 255) / 256, 256, 0, stream>>>(x, xbf, N);

    // grid: 8 XCD lanes x 49 tile-slots x 4 quarters (bijective remap inside)
    const int gemm_blocks = 8 * 49 * 4;   // 1568; 4 dead (tile 391)
    const int nd40 = N * 40;
    float invN = 1.0f / (float)N;
    const size_t WtM = (size_t)320 * KP;

    // pooled[0] = sum of raw x rows per graph
    pool_kernel<false><<<NGR, 320, 0, stream>>>(xbf, off, sc2, pooled);

    u16* g = bufA;
    u16* t = bufB;
    const u16* src = xbf;
    for (int l = 0; l < NL; ++l) {
        // gather (+BN2/ReLU of prev layer for l>0): src -> g
        if (l == 0)
            gather_kernel<false><<<(nd40 + 255) / 256, 256, 0, stream>>>(src, g, rowptr, col, sc2, N);
        else
            gather_kernel<true><<<(nd40 + 255) / 256, 256, 0, stream>>>(src, g, rowptr, col, sc2, N);
        // GEMM1 (+wave partials): g @ W1 -> t   (bias folded into BN)
        mfma_gemm_kernel<false><<<gemm_blocks, 256, 0, stream>>>(
            g, Wt + (size_t)l * WtM, sc1, t, psum, N);
        bnfin_kernel<<<D, 256, 0, stream>>>(psum, g1 + l * D, be1 + l * D, sc1, invN);
        // GEMM2 (BN1+ReLU on the fly, +wave partials): t @ W2 -> g
        mfma_gemm_kernel<true><<<gemm_blocks, 256, 0, stream>>>(
            t, Wt + (size_t)(NL + l) * WtM, sc1, g, psum, N);
        bnfin_kernel<<<D, 256, 0, stream>>>(psum, bng + l * D, bnb + l * D, sc2, invN);
        // pooled[l+1] = per-graph sum of relu(bn2(z_l)) via on-the-fly apply
        pool_kernel<true><<<NGR, 320, 0, stream>>>(g, off, sc2, pooled + (size_t)(l + 1) * NGR * D);
        src = g;
        u16* tmp = g; g = t; t = tmp;
    }
    readout_kernel<<<dim3(NGR / 4, NL + 1), 128, 0, stream>>>(pooled, off, fcW, out);
}